// Round 3
// baseline (1029.655 us; speedup 1.0000x reference)
//
#include <hip/hip_runtime.h>

// ReaxFF bond energy + segment_sum into atoms.
// N_BONDS = 16777216, N_ATOMS = 1048576, N_TYPES = 16.
//
// Strategy: device-scope fp atomics measured at ~20 G/s (R1: 814 us, WRITE_SIZE
// = 16M x 32B). Instead, privatize the 4 MB output per-XCD (8 replicas in d_ws),
// scatter with XCD-local L2 atomics (global_atomic_add_f32, no sc1), then reduce
// the replicas. Each block picks its replica via HW_REG_XCC_ID, so replica r is
// only ever touched by XCD r -> XCD-local L2 coherence is sufficient.

// Native clang vectors (HIP_vector_type is not accepted by
// __builtin_nontemporal_load).
typedef float f32x4 __attribute__((ext_vector_type(4)));
typedef int   i32x4 __attribute__((ext_vector_type(4)));

__device__ __forceinline__ unsigned get_xcc_id() {
    unsigned x;
    asm volatile("s_getreg_b32 %0, hwreg(HW_REG_XCC_ID)" : "=s"(x));
    return x & 7u;
}

// Plain (no sc0/sc1) global atomic: executes in the XCD-local L2.
__device__ __forceinline__ void l2AtomicAdd(float* addr, float val) {
    asm volatile("global_atomic_add_f32 %0, %1, off"
                 :: "v"(addr), "v"(val)
                 : "memory");
}

__device__ __forceinline__ float bond_e(int t, float bs, float bp, float bpp,
                                        const float* __restrict__ sp) {
    const float* p = sp + t * 5;
    float de_s = p[0], de_p = p[1], de_pp = p[2], p_be1 = p[3], p_be2 = p[4];
    // bs in (0.05, 1.0) -> strictly positive, fast pow/exp are safe.
    float pw = __powf(bs, p_be2);
    return -de_s * bs * __expf(p_be1 * (1.0f - pw)) - de_p * bp - de_pp * bpp;
}

template <bool USE_REPLICAS>
__global__ __launch_bounds__(256) void bond_energy_kernel(
        const i32x4*  __restrict__ bond_type,
        const i32x4*  __restrict__ atom_i,
        const f32x4*  __restrict__ bo_sigma,
        const f32x4*  __restrict__ bo_pi,
        const f32x4*  __restrict__ bo_pipi,
        const float*  __restrict__ bond_params,   // 16 x 5
        float*        __restrict__ replicas,      // 8 x n_atoms (or d_out if !USE_REPLICAS)
        int n4, int n_atoms) {
    __shared__ float sp[80];
    if (threadIdx.x < 80) sp[threadIdx.x] = bond_params[threadIdx.x];
    __syncthreads();

    float* rep = replicas;
    if (USE_REPLICAS) {
        rep += (size_t)get_xcc_id() * (size_t)n_atoms;
    }

    int i = blockIdx.x * blockDim.x + threadIdx.x;
    if (i >= n4) return;

    // Non-temporal streaming loads: don't evict the L2-resident replica.
    i32x4 t   = __builtin_nontemporal_load(&bond_type[i]);
    i32x4 a   = __builtin_nontemporal_load(&atom_i[i]);
    f32x4 bs  = __builtin_nontemporal_load(&bo_sigma[i]);
    f32x4 bp  = __builtin_nontemporal_load(&bo_pi[i]);
    f32x4 bpp = __builtin_nontemporal_load(&bo_pipi[i]);

    float e0 = bond_e(t.x, bs.x, bp.x, bpp.x, sp);
    float e1 = bond_e(t.y, bs.y, bp.y, bpp.y, sp);
    float e2 = bond_e(t.z, bs.z, bp.z, bpp.z, sp);
    float e3 = bond_e(t.w, bs.w, bp.w, bpp.w, sp);

    if (USE_REPLICAS) {
        l2AtomicAdd(&rep[a.x], e0);
        l2AtomicAdd(&rep[a.y], e1);
        l2AtomicAdd(&rep[a.z], e2);
        l2AtomicAdd(&rep[a.w], e3);
    } else {
        unsafeAtomicAdd(&rep[a.x], e0);
        unsafeAtomicAdd(&rep[a.y], e1);
        unsafeAtomicAdd(&rep[a.z], e2);
        unsafeAtomicAdd(&rep[a.w], e3);
    }
}

// Sum the 8 per-XCD replicas into d_out. float4-vectorized.
__global__ __launch_bounds__(256) void reduce_replicas_kernel(
        const f32x4* __restrict__ replicas,   // 8 x n4_atoms float4s
        f32x4*       __restrict__ out,
        int n4_atoms) {
    int i = blockIdx.x * blockDim.x + threadIdx.x;
    if (i >= n4_atoms) return;
    f32x4 s = (f32x4)(0.f);
#pragma unroll
    for (int r = 0; r < 8; ++r) {
        s += replicas[(size_t)r * n4_atoms + i];
    }
    out[i] = s;
}

__global__ __launch_bounds__(256) void zero_kernel(f32x4* __restrict__ p, int n4) {
    int i = blockIdx.x * blockDim.x + threadIdx.x;
    if (i < n4) p[i] = (f32x4)(0.f);
}

extern "C" void kernel_launch(void* const* d_in, const int* in_sizes, int n_in,
                              void* d_out, int out_size, void* d_ws, size_t ws_size,
                              hipStream_t stream) {
    const int*   bond_type   = (const int*)  d_in[0];
    const int*   atom_i      = (const int*)  d_in[1];
    const float* bo_sigma    = (const float*)d_in[2];
    const float* bo_pi       = (const float*)d_in[3];
    const float* bo_pipi     = (const float*)d_in[4];
    const float* bond_params = (const float*)d_in[5];
    float*       e_atom      = (float*)d_out;

    const int n_bonds = in_sizes[0];          // 16777216
    const int n_atoms = out_size;             // 1048576
    const int n4      = n_bonds / 4;
    const int tb      = 256;
    const int tg      = (n4 + tb - 1) / tb;

    const size_t rep_bytes = (size_t)8 * n_atoms * sizeof(float);

    if (ws_size >= rep_bytes) {
        float* replicas = (float*)d_ws;
        // Zero replicas (d_ws is re-poisoned to 0xAA before every call).
        int zn4 = (int)(rep_bytes / 16);
        zero_kernel<<<(zn4 + tb - 1) / tb, tb, 0, stream>>>((f32x4*)replicas, zn4);

        bond_energy_kernel<true><<<tg, tb, 0, stream>>>(
            (const i32x4*)bond_type, (const i32x4*)atom_i,
            (const f32x4*)bo_sigma, (const f32x4*)bo_pi, (const f32x4*)bo_pipi,
            bond_params, replicas, n4, n_atoms);

        int rn4 = n_atoms / 4;
        reduce_replicas_kernel<<<(rn4 + tb - 1) / tb, tb, 0, stream>>>(
            (const f32x4*)replicas, (f32x4*)e_atom, rn4);
    } else {
        // Fallback: device-scope atomics straight into d_out.
        int zn4 = n_atoms / 4;
        zero_kernel<<<(zn4 + tb - 1) / tb, tb, 0, stream>>>((f32x4*)e_atom, zn4);
        bond_energy_kernel<false><<<tg, tb, 0, stream>>>(
            (const i32x4*)bond_type, (const i32x4*)atom_i,
            (const f32x4*)bo_sigma, (const f32x4*)bo_pi, (const f32x4*)bo_pipi,
            bond_params, e_atom, n4, n_atoms);
    }
}

// Round 4
// 549.421 us; speedup vs baseline: 1.8741x; 1.8741x over previous
//
#include <hip/hip_runtime.h>

// ReaxFF bond energy + segment_sum. N_BONDS=16777216, N_ATOMS=1048576, N_TYPES=16.
//
// R1-R3 lesson: global fp atomics execute memory-side at 32B granule
// (WRITE_SIZE == 16M x 32B exactly, ~21 G atomics/s wall) regardless of scope.
// So: exact radix partition by atom>>11 into 512 buckets (no padding, exact
// scan-based layout, no global atomics), then per-bucket LDS fp32 accumulation.

typedef float f32x4 __attribute__((ext_vector_type(4)));
typedef int   i32x4 __attribute__((ext_vector_type(4)));

#define NB     512      // buckets; bucket covers 2048 atoms (shift 11)
#define RANGE  2048
#define SHIFT  11
#define CB     16384    // bonds per superblock (one block of pass A/B)
#define TB     256      // threads per block

__device__ __forceinline__ float bond_e(int t, float bs, float bp, float bpp,
                                        const float* __restrict__ sp) {
    const float* p = sp + t * 5;
    float de_s = p[0], de_p = p[1], de_pp = p[2], p_be1 = p[3], p_be2 = p[4];
    float pw = __powf(bs, p_be2);          // bs in (0.05,1) -> safe
    return -de_s * bs * __expf(p_be1 * (1.0f - pw)) - de_p * bp - de_pp * bpp;
}

__device__ __forceinline__ unsigned f32_to_bf16_bits(float f) {
    unsigned u = __float_as_uint(f);
    return ((u + 0x7FFFu + ((u >> 16) & 1u)) >> 16) & 0xFFFFu;
}

// ---- Pass A: per-superblock bucket counts ----
__global__ __launch_bounds__(TB) void count_kernel(
        const i32x4* __restrict__ atom_i, unsigned* __restrict__ counts,
        int round_start) {
    __shared__ unsigned hist[NB];
    for (int i = threadIdx.x; i < NB; i += TB) hist[i] = 0u;
    __syncthreads();
    int sb = blockIdx.x;
    long base4 = ((long)round_start + (long)sb * CB) >> 2;
#pragma unroll
    for (int it = 0; it < CB / (TB * 4); ++it) {
        i32x4 a = __builtin_nontemporal_load(&atom_i[base4 + it * TB + threadIdx.x]);
        atomicAdd(&hist[(unsigned)a.x >> SHIFT], 1u);
        atomicAdd(&hist[(unsigned)a.y >> SHIFT], 1u);
        atomicAdd(&hist[(unsigned)a.z >> SHIFT], 1u);
        atomicAdd(&hist[(unsigned)a.w >> SHIFT], 1u);
    }
    __syncthreads();
    for (int b = threadIdx.x; b < NB; b += TB)
        counts[(size_t)sb * NB + b] = hist[b];
}

// ---- S1: per-bucket exclusive scan over superblocks (blockDim == nsb) ----
__global__ void scan_cols_kernel(const unsigned* __restrict__ counts,
                                 unsigned* __restrict__ offs,
                                 unsigned* __restrict__ total, int nsb) {
    __shared__ unsigned sc[1024];
    int b = blockIdx.x, s = threadIdx.x;
    unsigned v = counts[(size_t)s * NB + b];
    sc[s] = v;
    __syncthreads();
    for (int off = 1; off < nsb; off <<= 1) {
        unsigned t = (s >= off) ? sc[s - off] : 0u;
        __syncthreads();
        sc[s] += t;
        __syncthreads();
    }
    offs[(size_t)s * NB + b] = sc[s] - v;
    if (s == nsb - 1) total[b] = sc[s];
}

// ---- S2: exclusive scan of bucket totals -> bucket bases (blockDim == NB) ----
__global__ void scan_base_kernel(const unsigned* __restrict__ total,
                                 unsigned* __restrict__ base) {
    __shared__ unsigned sc[NB];
    int b = threadIdx.x;
    unsigned v = total[b];
    sc[b] = v;
    __syncthreads();
    for (int off = 1; off < NB; off <<= 1) {
        unsigned t = (b >= off) ? sc[b - off] : 0u;
        __syncthreads();
        sc[b] += t;
        __syncthreads();
    }
    base[b] = sc[b] - v;
}

// ---- Pass B: compute e, partition into exact bucket runs ----
__global__ __launch_bounds__(TB) void partition_kernel(
        const i32x4* __restrict__ bt, const i32x4* __restrict__ ai,
        const f32x4* __restrict__ bs_, const f32x4* __restrict__ bp_,
        const f32x4* __restrict__ bpp_, const float* __restrict__ bond_params,
        const unsigned* __restrict__ offs, const unsigned* __restrict__ base,
        unsigned* __restrict__ arena, int round_start) {
    __shared__ float sp[80];
    __shared__ unsigned cur[NB];
    if (threadIdx.x < 80) sp[threadIdx.x] = bond_params[threadIdx.x];
    int sb = blockIdx.x;
    for (int b = threadIdx.x; b < NB; b += TB)
        cur[b] = base[b] + offs[(size_t)sb * NB + b];
    __syncthreads();
    long base4 = ((long)round_start + (long)sb * CB) >> 2;
#pragma unroll 2
    for (int it = 0; it < CB / (TB * 4); ++it) {
        long idx = base4 + it * TB + threadIdx.x;
        i32x4 t  = __builtin_nontemporal_load(&bt[idx]);
        i32x4 a  = __builtin_nontemporal_load(&ai[idx]);
        f32x4 s  = __builtin_nontemporal_load(&bs_[idx]);
        f32x4 p  = __builtin_nontemporal_load(&bp_[idx]);
        f32x4 pp = __builtin_nontemporal_load(&bpp_[idx]);
#pragma unroll
        for (int k = 0; k < 4; ++k) {
            int   tk  = t[k];
            unsigned ak = (unsigned)a[k];
            float e   = bond_e(tk, s[k], p[k], pp[k], sp);
            unsigned b = ak >> SHIFT;
            unsigned pos = atomicAdd(&cur[b], 1u);
            arena[pos] = ((ak & (RANGE - 1u)) << 16) | f32_to_bf16_bits(e);
        }
    }
}

// ---- Pass C: per-bucket LDS accumulation -> output slice ----
__global__ __launch_bounds__(TB) void accum_kernel(
        const unsigned* __restrict__ arena, const unsigned* __restrict__ base,
        const unsigned* __restrict__ total, float* __restrict__ out,
        int add_prev) {
    __shared__ float acc[RANGE];
    int b = blockIdx.x;
    for (int i = threadIdx.x; i < RANGE; i += TB) acc[i] = 0.f;
    __syncthreads();
    unsigned s0 = base[b], n = total[b];
    for (unsigned j = threadIdx.x; j < n; j += TB) {
        unsigned e = arena[s0 + j];
        atomicAdd(&acc[e >> 16], __uint_as_float((e & 0xFFFFu) << 16));
    }
    __syncthreads();
    size_t ob = (size_t)b * RANGE;
    for (int i = threadIdx.x; i < RANGE; i += TB) {
        float v = acc[i];
        if (add_prev) v += out[ob + i];
        out[ob + i] = v;
    }
}

// ---- Fallback path (R1): zero + device atomics ----
__global__ __launch_bounds__(TB) void zero_kernel(f32x4* __restrict__ p, int n4) {
    int i = blockIdx.x * blockDim.x + threadIdx.x;
    if (i < n4) p[i] = (f32x4)(0.f);
}

__global__ __launch_bounds__(TB) void atomic_fallback_kernel(
        const i32x4* __restrict__ bt, const i32x4* __restrict__ ai,
        const f32x4* __restrict__ bs_, const f32x4* __restrict__ bp_,
        const f32x4* __restrict__ bpp_, const float* __restrict__ bond_params,
        float* __restrict__ out, int n4) {
    __shared__ float sp[80];
    if (threadIdx.x < 80) sp[threadIdx.x] = bond_params[threadIdx.x];
    __syncthreads();
    int i = blockIdx.x * blockDim.x + threadIdx.x;
    if (i >= n4) return;
    i32x4 t  = bt[i]; i32x4 a = ai[i];
    f32x4 s  = bs_[i]; f32x4 p = bp_[i]; f32x4 pp = bpp_[i];
    unsafeAtomicAdd(&out[a.x], bond_e(t.x, s.x, p.x, pp.x, sp));
    unsafeAtomicAdd(&out[a.y], bond_e(t.y, s.y, p.y, pp.y, sp));
    unsafeAtomicAdd(&out[a.z], bond_e(t.z, s.z, p.z, pp.z, sp));
    unsafeAtomicAdd(&out[a.w], bond_e(t.w, s.w, p.w, pp.w, sp));
}

extern "C" void kernel_launch(void* const* d_in, const int* in_sizes, int n_in,
                              void* d_out, int out_size, void* d_ws, size_t ws_size,
                              hipStream_t stream) {
    const int*   bond_type   = (const int*)  d_in[0];
    const int*   atom_i      = (const int*)  d_in[1];
    const float* bo_sigma    = (const float*)d_in[2];
    const float* bo_pi       = (const float*)d_in[3];
    const float* bo_pipi     = (const float*)d_in[4];
    const float* bond_params = (const float*)d_in[5];
    float*       e_atom      = (float*)d_out;

    const int n_bonds = in_sizes[0];
    const int n_atoms = out_size;

    // Pick fewest rounds whose workspace fits.
    int NR = 0;
    if (n_atoms == (NB << SHIFT)) {
        const int cands[4] = {1, 2, 4, 8};
        for (int ci = 0; ci < 4; ++ci) {
            int r = cands[ci];
            if (n_bonds % (r * CB)) continue;
            int cpr = n_bonds / r, nsb = cpr / CB;
            if (nsb > 1024 || nsb < 64) continue;
            size_t need = (size_t)cpr * 4 + 2 * (size_t)nsb * NB * 4 + 2 * (size_t)NB * 4;
            if (need <= ws_size) { NR = r; break; }
        }
    }

    if (NR) {
        const int cpr = n_bonds / NR, nsb = cpr / CB;
        unsigned* arena  = (unsigned*)d_ws;
        unsigned* counts = arena + cpr;
        unsigned* offs   = counts + (size_t)nsb * NB;
        unsigned* total  = offs + (size_t)nsb * NB;
        unsigned* basep  = total + NB;
        for (int r = 0; r < NR; ++r) {
            int rs = r * cpr;
            count_kernel<<<nsb, TB, 0, stream>>>((const i32x4*)atom_i, counts, rs);
            scan_cols_kernel<<<NB, nsb, 0, stream>>>(counts, offs, total, nsb);
            scan_base_kernel<<<1, NB, 0, stream>>>(total, basep);
            partition_kernel<<<nsb, TB, 0, stream>>>(
                (const i32x4*)bond_type, (const i32x4*)atom_i,
                (const f32x4*)bo_sigma, (const f32x4*)bo_pi, (const f32x4*)bo_pipi,
                bond_params, offs, basep, arena, rs);
            accum_kernel<<<NB, TB, 0, stream>>>(arena, basep, total, e_atom, r ? 1 : 0);
        }
    } else {
        int zn4 = n_atoms / 4;
        zero_kernel<<<(zn4 + TB - 1) / TB, TB, 0, stream>>>((f32x4*)e_atom, zn4);
        int n4 = n_bonds / 4;
        atomic_fallback_kernel<<<(n4 + TB - 1) / TB, TB, 0, stream>>>(
            (const i32x4*)bond_type, (const i32x4*)atom_i,
            (const f32x4*)bo_sigma, (const f32x4*)bo_pi, (const f32x4*)bo_pipi,
            bond_params, e_atom, n4);
    }
}

// Round 5
// 491.742 us; speedup vs baseline: 2.0939x; 1.1173x over previous
//
#include <hip/hip_runtime.h>

// ReaxFF bond energy + segment_sum. N_BONDS=16777216, N_ATOMS=1048576, N_TYPES=16.
//
// R1-R3: global fp atomics are memory-side, 32B granule (~21 G/s wall).
// R4: exact radix partition worked (549 us) but per-element 4B scattered stores
//     write-amplified to 373 MB (partial-sector L2 evictions).
// R5: block-local counting sort in LDS; bucket runs written with coalesced,
//     32B-sector-aligned stores (cells padded to 8 elems, zero sentinels).

typedef float f32x4 __attribute__((ext_vector_type(4)));
typedef int   i32x4 __attribute__((ext_vector_type(4)));

#define NB     512      // buckets; bucket covers 2048 atoms
#define RANGE  2048
#define SHIFT  11
#define CB     16384    // bonds per superblock
#define TB     256
#define PADQ   8u       // cell padding quantum (8 elems = 32 B = 1 HBM sector)

__device__ __forceinline__ float bond_e(int t, float bs, float bp, float bpp,
                                        const float* __restrict__ sp) {
    const float* p = sp + t * 5;
    float de_s = p[0], de_p = p[1], de_pp = p[2], p_be1 = p[3], p_be2 = p[4];
    float pw = __powf(bs, p_be2);          // bs in (0.05,1) -> safe
    return -de_s * bs * __expf(p_be1 * (1.0f - pw)) - de_p * bp - de_pp * bpp;
}

__device__ __forceinline__ unsigned f32_to_bf16_bits(float f) {
    unsigned u = __float_as_uint(f);
    return ((u + 0x7FFFu + ((u >> 16) & 1u)) >> 16) & 0xFFFFu;
}

// ---- Pass A: per-superblock bucket counts (per-wave LDS hist) ----
__global__ __launch_bounds__(TB) void count_kernel(
        const i32x4* __restrict__ atom_i, unsigned* __restrict__ counts,
        int round_start) {
    __shared__ unsigned hist[4][NB];
    int tid = threadIdx.x, w = tid >> 6;
    for (int i = tid; i < 4 * NB; i += TB) hist[i >> 9][i & (NB - 1)] = 0u;
    __syncthreads();
    long base4 = ((long)round_start + (long)blockIdx.x * CB) >> 2;
#pragma unroll
    for (int it = 0; it < CB / (TB * 4); ++it) {
        i32x4 a = __builtin_nontemporal_load(&atom_i[base4 + it * TB + tid]);
        atomicAdd(&hist[w][(unsigned)a.x >> SHIFT], 1u);
        atomicAdd(&hist[w][(unsigned)a.y >> SHIFT], 1u);
        atomicAdd(&hist[w][(unsigned)a.z >> SHIFT], 1u);
        atomicAdd(&hist[w][(unsigned)a.w >> SHIFT], 1u);
    }
    __syncthreads();
    for (int b = tid; b < NB; b += TB)
        counts[(size_t)blockIdx.x * NB + b] =
            hist[0][b] + hist[1][b] + hist[2][b] + hist[3][b];
}

// ---- S1: per-bucket exclusive scan of PADDED counts over superblocks ----
__global__ void scan_cols_kernel(const unsigned* __restrict__ counts,
                                 unsigned* __restrict__ offs,
                                 unsigned* __restrict__ total, int nsb) {
    __shared__ unsigned sc[1024];
    int b = blockIdx.x, s = threadIdx.x;
    unsigned v = (counts[(size_t)s * NB + b] + PADQ - 1u) & ~(PADQ - 1u);
    sc[s] = v;
    __syncthreads();
    for (int off = 1; off < nsb; off <<= 1) {
        unsigned t = (s >= off) ? sc[s - off] : 0u;
        __syncthreads();
        sc[s] += t;
        __syncthreads();
    }
    offs[(size_t)s * NB + b] = sc[s] - v;
    if (s == nsb - 1) total[b] = sc[s];
}

// ---- S2: exclusive scan of padded bucket totals -> bucket bases ----
__global__ void scan_base_kernel(const unsigned* __restrict__ total,
                                 unsigned* __restrict__ base) {
    __shared__ unsigned sc[NB];
    int b = threadIdx.x;
    unsigned v = total[b];
    sc[b] = v;
    __syncthreads();
    for (int off = 1; off < NB; off <<= 1) {
        unsigned t = (b >= off) ? sc[b - off] : 0u;
        __syncthreads();
        sc[b] += t;
        __syncthreads();
    }
    base[b] = sc[b] - v;
}

// ---- Pass B: compute e, LDS counting sort, coalesced padded run writes ----
__global__ __launch_bounds__(TB) void partition_kernel(
        const i32x4* __restrict__ bt, const i32x4* __restrict__ ai,
        const f32x4* __restrict__ bs_, const f32x4* __restrict__ bp_,
        const f32x4* __restrict__ bpp_, const float* __restrict__ bond_params,
        const unsigned* __restrict__ counts, const unsigned* __restrict__ offs,
        const unsigned* __restrict__ base, unsigned* __restrict__ arena,
        int round_start) {
    __shared__ float    sp[80];
    __shared__ unsigned cnt[NB], lstart[NB], cur[NB], part[TB];
    __shared__ unsigned sorted[CB];     // 64 KB

    int tid = threadIdx.x, sb = blockIdx.x;
    if (tid < 80) sp[tid] = bond_params[tid];
    // load block histogram (computed by pass A)
    unsigned c0 = counts[(size_t)sb * NB + 2 * tid];
    unsigned c1 = counts[(size_t)sb * NB + 2 * tid + 1];
    cnt[2 * tid] = c0; cnt[2 * tid + 1] = c1;
    part[tid] = c0 + c1;
    __syncthreads();
    // Hillis-Steele inclusive scan of 256 pair-sums
    for (int off = 1; off < TB; off <<= 1) {
        unsigned t = (tid >= off) ? part[tid - off] : 0u;
        __syncthreads();
        part[tid] += t;
        __syncthreads();
    }
    unsigned excl = part[tid] - (c0 + c1);
    lstart[2 * tid] = excl;          cur[2 * tid] = excl;
    lstart[2 * tid + 1] = excl + c0; cur[2 * tid + 1] = excl + c0;
    __syncthreads();

    long base4 = ((long)round_start + (long)sb * CB) >> 2;
#pragma unroll 2
    for (int it = 0; it < CB / (TB * 4); ++it) {
        long idx = base4 + it * TB + tid;
        i32x4 t  = __builtin_nontemporal_load(&bt[idx]);
        i32x4 a  = __builtin_nontemporal_load(&ai[idx]);
        f32x4 s  = __builtin_nontemporal_load(&bs_[idx]);
        f32x4 p  = __builtin_nontemporal_load(&bp_[idx]);
        f32x4 pp = __builtin_nontemporal_load(&bpp_[idx]);
#pragma unroll
        for (int k = 0; k < 4; ++k) {
            unsigned ak = (unsigned)a[k];
            float e = bond_e(t[k], s[k], p[k], pp[k], sp);
            unsigned b = ak >> SHIFT;
            unsigned pos = atomicAdd(&cur[b], 1u);
            sorted[pos] = ((ak & (RANGE - 1u)) << 16) | f32_to_bf16_bits(e);
        }
    }
    __syncthreads();

    // coalesced copy-out: wave w handles buckets w, w+4, ...
    int w = tid >> 6, lane = tid & 63;
    for (int b = w; b < NB; b += 4) {
        unsigned len  = cnt[b];
        unsigned plen = (len + PADQ - 1u) & ~(PADQ - 1u);
        unsigned g    = base[b] + offs[(size_t)sb * NB + b];
        unsigned ls   = lstart[b];
        for (unsigned j = lane; j < plen; j += 64u)
            arena[g + j] = (j < len) ? sorted[ls + j] : 0u;
    }
}

// ---- Pass C: per-bucket LDS accumulation (per-wave replicas) ----
__global__ __launch_bounds__(TB) void accum_kernel(
        const unsigned* __restrict__ arena, const unsigned* __restrict__ base,
        const unsigned* __restrict__ total, float* __restrict__ out,
        int add_prev) {
    __shared__ float acc[4][RANGE];     // 32 KB
    int tid = threadIdx.x, w = tid >> 6, b = blockIdx.x;
    for (int i = tid; i < RANGE; i += TB) {
        acc[0][i] = 0.f; acc[1][i] = 0.f; acc[2][i] = 0.f; acc[3][i] = 0.f;
    }
    __syncthreads();
    unsigned s0 = base[b], n = total[b];          // both multiples of 8
    const uint4* src = (const uint4*)(arena + s0);
    for (unsigned j = tid; j < (n >> 2); j += TB) {
        uint4 e = src[j];
        if (e.x) atomicAdd(&acc[w][e.x >> 16], __uint_as_float((e.x & 0xFFFFu) << 16));
        if (e.y) atomicAdd(&acc[w][e.y >> 16], __uint_as_float((e.y & 0xFFFFu) << 16));
        if (e.z) atomicAdd(&acc[w][e.z >> 16], __uint_as_float((e.z & 0xFFFFu) << 16));
        if (e.w) atomicAdd(&acc[w][e.w >> 16], __uint_as_float((e.w & 0xFFFFu) << 16));
    }
    __syncthreads();
    size_t ob = (size_t)b * RANGE;
    for (int i = tid; i < RANGE; i += TB) {
        float v = acc[0][i] + acc[1][i] + acc[2][i] + acc[3][i];
        if (add_prev) v += out[ob + i];
        out[ob + i] = v;
    }
}

// ---- Fallback path: zero + device atomics ----
__global__ __launch_bounds__(TB) void zero_kernel(f32x4* __restrict__ p, int n4) {
    int i = blockIdx.x * blockDim.x + threadIdx.x;
    if (i < n4) p[i] = (f32x4)(0.f);
}

__global__ __launch_bounds__(TB) void atomic_fallback_kernel(
        const i32x4* __restrict__ bt, const i32x4* __restrict__ ai,
        const f32x4* __restrict__ bs_, const f32x4* __restrict__ bp_,
        const f32x4* __restrict__ bpp_, const float* __restrict__ bond_params,
        float* __restrict__ out, int n4) {
    __shared__ float sp[80];
    if (threadIdx.x < 80) sp[threadIdx.x] = bond_params[threadIdx.x];
    __syncthreads();
    int i = blockIdx.x * blockDim.x + threadIdx.x;
    if (i >= n4) return;
    i32x4 t  = bt[i]; i32x4 a = ai[i];
    f32x4 s  = bs_[i]; f32x4 p = bp_[i]; f32x4 pp = bpp_[i];
    unsafeAtomicAdd(&out[a.x], bond_e(t.x, s.x, p.x, pp.x, sp));
    unsafeAtomicAdd(&out[a.y], bond_e(t.y, s.y, p.y, pp.y, sp));
    unsafeAtomicAdd(&out[a.z], bond_e(t.z, s.z, p.z, pp.z, sp));
    unsafeAtomicAdd(&out[a.w], bond_e(t.w, s.w, p.w, pp.w, sp));
}

extern "C" void kernel_launch(void* const* d_in, const int* in_sizes, int n_in,
                              void* d_out, int out_size, void* d_ws, size_t ws_size,
                              hipStream_t stream) {
    const int*   bond_type   = (const int*)  d_in[0];
    const int*   atom_i      = (const int*)  d_in[1];
    const float* bo_sigma    = (const float*)d_in[2];
    const float* bo_pi       = (const float*)d_in[3];
    const float* bo_pipi     = (const float*)d_in[4];
    const float* bond_params = (const float*)d_in[5];
    float*       e_atom      = (float*)d_out;

    const int n_bonds = in_sizes[0];
    const int n_atoms = out_size;

    // Pick fewest rounds whose (worst-case padded) workspace fits.
    int NR = 0;
    if (n_atoms == (NB << SHIFT)) {
        const int cands[4] = {1, 2, 4, 8};
        for (int ci = 0; ci < 4; ++ci) {
            int r = cands[ci];
            if (n_bonds % (r * CB)) continue;
            int cpr = n_bonds / r, nsb = cpr / CB;
            if (nsb > 1024 || nsb < 64) continue;
            size_t arena_worst = (size_t)cpr + (size_t)(PADQ - 1) * NB * nsb;
            size_t need = arena_worst * 4 + 2 * (size_t)nsb * NB * 4 + 2 * (size_t)NB * 4;
            if (need <= ws_size) { NR = r; break; }
        }
    }

    if (NR) {
        const int cpr = n_bonds / NR, nsb = cpr / CB;
        size_t arena_worst = (size_t)cpr + (size_t)(PADQ - 1) * NB * nsb;
        unsigned* arena  = (unsigned*)d_ws;
        unsigned* counts = arena + arena_worst;
        unsigned* offs   = counts + (size_t)nsb * NB;
        unsigned* total  = offs + (size_t)nsb * NB;
        unsigned* basep  = total + NB;
        for (int r = 0; r < NR; ++r) {
            int rs = r * cpr;
            count_kernel<<<nsb, TB, 0, stream>>>((const i32x4*)atom_i, counts, rs);
            scan_cols_kernel<<<NB, nsb, 0, stream>>>(counts, offs, total, nsb);
            scan_base_kernel<<<1, NB, 0, stream>>>(total, basep);
            partition_kernel<<<nsb, TB, 0, stream>>>(
                (const i32x4*)bond_type, (const i32x4*)atom_i,
                (const f32x4*)bo_sigma, (const f32x4*)bo_pi, (const f32x4*)bo_pipi,
                bond_params, counts, offs, basep, arena, rs);
            accum_kernel<<<NB, TB, 0, stream>>>(arena, basep, total, e_atom, r ? 1 : 0);
        }
    } else {
        int zn4 = n_atoms / 4;
        zero_kernel<<<(zn4 + TB - 1) / TB, TB, 0, stream>>>((f32x4*)e_atom, zn4);
        int n4 = n_bonds / 4;
        atomic_fallback_kernel<<<(n4 + TB - 1) / TB, TB, 0, stream>>>(
            (const i32x4*)bond_type, (const i32x4*)atom_i,
            (const f32x4*)bo_sigma, (const f32x4*)bo_pi, (const f32x4*)bo_pipi,
            bond_params, e_atom, n4);
    }
}

// Round 6
// 440.026 us; speedup vs baseline: 2.3400x; 1.1175x over previous
//
#include <hip/hip_runtime.h>

// ReaxFF bond energy + segment_sum. N_BONDS=16777216, N_ATOMS=1048576, N_TYPES=16.
//
// R1-R3: global fp atomics are memory-side, 32B granule (~21 G/s wall).
// R4: exact radix partition, but 4B scattered stores write-amplified (373 MB).
// R5: LDS counting sort + sector-aligned run writes (WRITE 72 MB) -> 181 us
//     partition, but occupancy 21% (73 KB LDS), VALU/LDS-latency bound.
// R6: CB=8192 (39 KB LDS -> 4 blocks/CU), params via 2 LDS ops not 5,
//     16-lane-per-bucket copy-out, scan_base folded into partition/accum.

typedef float f32x4 __attribute__((ext_vector_type(4)));
typedef int   i32x4 __attribute__((ext_vector_type(4)));
typedef unsigned u32;

#define NB     512      // buckets; bucket covers 2048 atoms
#define RANGE  2048
#define SHIFT  11
#define CB     8192     // bonds per superblock
#define TB     256
#define PADQ   8u       // run padding quantum (8 elems = 32 B = 1 HBM sector)

__device__ __forceinline__ u32 f32_to_bf16_bits(float f) {
    u32 u = __float_as_uint(f);
    return ((u + 0x7FFFu + ((u >> 16) & 1u)) >> 16) & 0xFFFFu;
}

// ---- Pass A: per-superblock bucket counts (per-wave LDS hist) ----
__global__ __launch_bounds__(TB) void count_kernel(
        const i32x4* __restrict__ atom_i, u32* __restrict__ counts,
        int round_start) {
    __shared__ u32 hist[4][NB];
    int tid = threadIdx.x, w = tid >> 6;
    for (int i = tid; i < 4 * NB; i += TB) ((u32*)hist)[i] = 0u;
    __syncthreads();
    long base4 = ((long)round_start + (long)blockIdx.x * CB) >> 2;
#pragma unroll
    for (int it = 0; it < CB / (TB * 4); ++it) {
        i32x4 a = __builtin_nontemporal_load(&atom_i[base4 + it * TB + tid]);
        atomicAdd(&hist[w][(u32)a.x >> SHIFT], 1u);
        atomicAdd(&hist[w][(u32)a.y >> SHIFT], 1u);
        atomicAdd(&hist[w][(u32)a.z >> SHIFT], 1u);
        atomicAdd(&hist[w][(u32)a.w >> SHIFT], 1u);
    }
    __syncthreads();
    for (int b = tid; b < NB; b += TB)
        counts[(size_t)blockIdx.x * NB + b] =
            hist[0][b] + hist[1][b] + hist[2][b] + hist[3][b];
}

// ---- S1: per-bucket exclusive scan of PADDED counts over superblocks ----
// 256 threads, each handles nsb/256 consecutive superblocks.
__global__ __launch_bounds__(TB) void scan_cols_kernel(
        const u32* __restrict__ counts, u32* __restrict__ offs,
        u32* __restrict__ total, int nsb) {
    __shared__ u32 sc[TB];
    int b = blockIdx.x, t = threadIdx.x;
    int vpt = nsb >> 8;                 // nsb multiple of 256, vpt <= 16
    u32 v[16];
    u32 s = 0;
    for (int k = 0; k < vpt; ++k) {
        u32 c = counts[(size_t)(t * vpt + k) * NB + b];
        c = (c + PADQ - 1u) & ~(PADQ - 1u);
        v[k] = s; s += c;
    }
    sc[t] = s;
    __syncthreads();
    for (int off = 1; off < TB; off <<= 1) {
        u32 u = (t >= off) ? sc[t - off] : 0u;
        __syncthreads();
        sc[t] += u;
        __syncthreads();
    }
    u32 excl = sc[t] - s;
    for (int k = 0; k < vpt; ++k)
        offs[(size_t)(t * vpt + k) * NB + b] = excl + v[k];
    if (t == TB - 1) total[b] = sc[t];
}

// ---- Pass B: compute e, LDS counting sort, coalesced padded run writes ----
__global__ __launch_bounds__(TB, 4) void partition_kernel(
        const i32x4* __restrict__ bt, const i32x4* __restrict__ ai,
        const f32x4* __restrict__ bs_, const f32x4* __restrict__ bp_,
        const f32x4* __restrict__ bpp_, const float* __restrict__ bond_params,
        const u32* __restrict__ counts, const u32* __restrict__ offs,
        const u32* __restrict__ total, u32* __restrict__ arena,
        int round_start) {
    __shared__ u32   sorted[CB];        // 32 KB
    __shared__ u32   cnt[NB], cur[NB], gstart[NB];
    __shared__ u32   scanb[TB];
    __shared__ float4 sp_a[16];         // de_s, de_p, de_pp, p_be1
    __shared__ float  sp_b[16];         // p_be2

    int tid = threadIdx.x, sb = blockIdx.x;
    if (tid < 16) {
        const float* p = bond_params + tid * 5;
        sp_a[tid] = make_float4(p[0], p[1], p[2], p[3]);
        sp_b[tid] = p[4];
    }
    // scan 1: count row -> cursor starts (local layout)
    u32 c0 = counts[(size_t)sb * NB + 2 * tid];
    u32 c1 = counts[(size_t)sb * NB + 2 * tid + 1];
    cnt[2 * tid] = c0; cnt[2 * tid + 1] = c1;
    scanb[tid] = c0 + c1;
    __syncthreads();
    for (int off = 1; off < TB; off <<= 1) {
        u32 u = (tid >= off) ? scanb[tid - off] : 0u;
        __syncthreads();
        scanb[tid] += u;
        __syncthreads();
    }
    u32 excl = scanb[tid] - (c0 + c1);
    cur[2 * tid] = excl; cur[2 * tid + 1] = excl + c0;
    __syncthreads();
    // scan 2: padded bucket totals -> global bucket base, + offs row -> gstart
    u32 t0 = total[2 * tid], t1 = total[2 * tid + 1];
    scanb[tid] = t0 + t1;
    __syncthreads();
    for (int off = 1; off < TB; off <<= 1) {
        u32 u = (tid >= off) ? scanb[tid - off] : 0u;
        __syncthreads();
        scanb[tid] += u;
        __syncthreads();
    }
    u32 excl2 = scanb[tid] - (t0 + t1);
    gstart[2 * tid]     = excl2 + offs[(size_t)sb * NB + 2 * tid];
    gstart[2 * tid + 1] = excl2 + t0 + offs[(size_t)sb * NB + 2 * tid + 1];
    __syncthreads();

    long base4 = ((long)round_start + (long)sb * CB) >> 2;
#pragma unroll
    for (int it = 0; it < CB / (TB * 4); ++it) {
        long idx = base4 + it * TB + tid;
        i32x4 t  = __builtin_nontemporal_load(&bt[idx]);
        i32x4 a  = __builtin_nontemporal_load(&ai[idx]);
        f32x4 s  = __builtin_nontemporal_load(&bs_[idx]);
        f32x4 p  = __builtin_nontemporal_load(&bp_[idx]);
        f32x4 pp = __builtin_nontemporal_load(&bpp_[idx]);
#pragma unroll
        for (int k = 0; k < 4; ++k) {
            u32 ak = (u32)a[k];
            float4 pa = sp_a[t[k]];      // one ds_read_b128
            float  pb = sp_b[t[k]];      // one ds_read_b32
            float pw = __powf(s[k], pb); // s in (0.05,1) -> safe
            float e  = -pa.x * s[k] * __expf(pa.w * (1.0f - pw))
                       - pa.y * p[k] - pa.z * pp[k];
            u32 b = ak >> SHIFT;
            u32 pos = atomicAdd(&cur[b], 1u);
            sorted[pos] = ((ak & (RANGE - 1u)) << 16) | f32_to_bf16_bits(e);
        }
    }
    __syncthreads();

    // copy-out: 16 lanes per bucket, 4 buckets per wave concurrently
    int w = tid >> 6, lane = tid & 63;
    int gi = lane >> 4, j0 = lane & 15;
    for (int b = w * 4 + gi; b < NB; b += 16) {
        u32 end = cur[b], len = cnt[b], ls = end - len;
        u32 plen = (len + PADQ - 1u) & ~(PADQ - 1u);
        u32 g = gstart[b];
        for (u32 j = j0; j < plen; j += 16u)
            arena[g + j] = (j < len) ? sorted[ls + j] : 0u;
    }
}

// ---- Pass C: per-bucket LDS accumulation (per-wave replicas) ----
__global__ __launch_bounds__(TB, 4) void accum_kernel(
        const u32* __restrict__ arena, const u32* __restrict__ total,
        float* __restrict__ out, int add_prev) {
    __shared__ float acc[4][RANGE];     // 32 KB
    __shared__ u32 red[TB];
    int tid = threadIdx.x, w = tid >> 6, b = blockIdx.x;
    // base[b] = sum of padded totals below b (block reduction, not scan)
    u32 part = 0;
    for (int i = tid; i < b; i += TB) part += total[i];
    red[tid] = part;
    for (int i = tid; i < RANGE; i += TB) {
        acc[0][i] = 0.f; acc[1][i] = 0.f; acc[2][i] = 0.f; acc[3][i] = 0.f;
    }
    __syncthreads();
    for (int s = TB / 2; s > 0; s >>= 1) {
        if (tid < s) red[tid] += red[tid + s];
        __syncthreads();
    }
    u32 s0 = red[0];
    u32 n  = total[b];                  // multiple of 8
    const uint4* src = (const uint4*)(arena + s0);
    for (u32 j = tid; j < (n >> 2); j += TB) {
        uint4 e = src[j];
        if (e.x) atomicAdd(&acc[w][e.x >> 16], __uint_as_float((e.x & 0xFFFFu) << 16));
        if (e.y) atomicAdd(&acc[w][e.y >> 16], __uint_as_float((e.y & 0xFFFFu) << 16));
        if (e.z) atomicAdd(&acc[w][e.z >> 16], __uint_as_float((e.z & 0xFFFFu) << 16));
        if (e.w) atomicAdd(&acc[w][e.w >> 16], __uint_as_float((e.w & 0xFFFFu) << 16));
    }
    __syncthreads();
    size_t ob = (size_t)b * RANGE;
    for (int i = tid; i < RANGE; i += TB) {
        float v = acc[0][i] + acc[1][i] + acc[2][i] + acc[3][i];
        if (add_prev) v += out[ob + i];
        out[ob + i] = v;
    }
}

// ---- Fallback path: zero + device atomics ----
__global__ __launch_bounds__(TB) void zero_kernel(f32x4* __restrict__ p, int n4) {
    int i = blockIdx.x * blockDim.x + threadIdx.x;
    if (i < n4) p[i] = (f32x4)(0.f);
}

__global__ __launch_bounds__(TB) void atomic_fallback_kernel(
        const i32x4* __restrict__ bt, const i32x4* __restrict__ ai,
        const f32x4* __restrict__ bs_, const f32x4* __restrict__ bp_,
        const f32x4* __restrict__ bpp_, const float* __restrict__ bond_params,
        float* __restrict__ out, int n4) {
    __shared__ float sp[80];
    if (threadIdx.x < 80) sp[threadIdx.x] = bond_params[threadIdx.x];
    __syncthreads();
    int i = blockIdx.x * blockDim.x + threadIdx.x;
    if (i >= n4) return;
    i32x4 t  = bt[i]; i32x4 a = ai[i];
    f32x4 s  = bs_[i]; f32x4 p = bp_[i]; f32x4 pp = bpp_[i];
#pragma unroll
    for (int k = 0; k < 4; ++k) {
        const float* pr = sp + t[k] * 5;
        float pw = __powf(s[k], pr[4]);
        float e  = -pr[0] * s[k] * __expf(pr[3] * (1.0f - pw))
                   - pr[1] * p[k] - pr[2] * pp[k];
        unsafeAtomicAdd(&out[a[k]], e);
    }
}

extern "C" void kernel_launch(void* const* d_in, const int* in_sizes, int n_in,
                              void* d_out, int out_size, void* d_ws, size_t ws_size,
                              hipStream_t stream) {
    const int*   bond_type   = (const int*)  d_in[0];
    const int*   atom_i      = (const int*)  d_in[1];
    const float* bo_sigma    = (const float*)d_in[2];
    const float* bo_pi       = (const float*)d_in[3];
    const float* bo_pipi     = (const float*)d_in[4];
    const float* bond_params = (const float*)d_in[5];
    float*       e_atom      = (float*)d_out;

    const int n_bonds = in_sizes[0];
    const int n_atoms = out_size;

    // Pick fewest rounds whose (worst-case padded) workspace fits.
    int NR = 0;
    if (n_atoms == (NB << SHIFT)) {
        const int cands[5] = {1, 2, 4, 8, 16};
        for (int ci = 0; ci < 5; ++ci) {
            int r = cands[ci];
            if (n_bonds % (r * CB)) continue;
            int cpr = n_bonds / r, nsb = cpr / CB;
            if (nsb % 256 || nsb < 256 || nsb > 4096) continue;
            size_t arena_worst = (size_t)cpr + (size_t)(PADQ - 1) * NB * nsb;
            size_t need = arena_worst * 4 + 2 * (size_t)nsb * NB * 4 + (size_t)NB * 4;
            if (need <= ws_size) { NR = r; break; }
        }
    }

    if (NR) {
        const int cpr = n_bonds / NR, nsb = cpr / CB;
        size_t arena_worst = (size_t)cpr + (size_t)(PADQ - 1) * NB * nsb;
        u32* arena  = (u32*)d_ws;
        u32* counts = arena + arena_worst;
        u32* offs   = counts + (size_t)nsb * NB;
        u32* total  = offs + (size_t)nsb * NB;
        for (int r = 0; r < NR; ++r) {
            int rs = r * cpr;
            count_kernel<<<nsb, TB, 0, stream>>>((const i32x4*)atom_i, counts, rs);
            scan_cols_kernel<<<NB, TB, 0, stream>>>(counts, offs, total, nsb);
            partition_kernel<<<nsb, TB, 0, stream>>>(
                (const i32x4*)bond_type, (const i32x4*)atom_i,
                (const f32x4*)bo_sigma, (const f32x4*)bo_pi, (const f32x4*)bo_pipi,
                bond_params, counts, offs, total, arena, rs);
            accum_kernel<<<NB, TB, 0, stream>>>(arena, total, e_atom, r ? 1 : 0);
        }
    } else {
        int zn4 = n_atoms / 4;
        zero_kernel<<<(zn4 + TB - 1) / TB, TB, 0, stream>>>((f32x4*)e_atom, zn4);
        int n4 = n_bonds / 4;
        atomic_fallback_kernel<<<(n4 + TB - 1) / TB, TB, 0, stream>>>(
            (const i32x4*)bond_type, (const i32x4*)atom_i,
            (const f32x4*)bo_sigma, (const f32x4*)bo_pi, (const f32x4*)bo_pipi,
            bond_params, e_atom, n4);
    }
}